// Round 6
// baseline (205.090 us; speedup 1.0000x reference)
//
#include <hip/hip_runtime.h>

// SoftTopK: x (8,1024,256) f32, noise (8,1024,8,256) f32
// perturbed = x + noise*1e-4 ; idx = smallest-16 indices (stable) per (b,n,s)
// out (8,1024,16,256) f32 = one_hot(idx).mean over s
//
// One block per (b,n). 4 waves; each wave runs TWO independent selection
// chains (samples 2w, 2w+1) interleaved for ILP. 4 elems/lane (float4).
// Per round: per-lane min+slot (<= prefers lower slot), 64-lane min via
// pure-DPP cascade (lane 63 -> readlane -> SGPR), winner lane via
// ballot+ctz (lowest lane), winner slot via dynamic readlane. All
// captures/invalidations branchless (cndmask vs SGPR m_win). This
// reproduces lax.top_k's stable (value asc, index asc) order bit-exactly.
// __fadd_rn/__fmul_rn forbid FMA contraction so perturbed values
// bit-match the fp32 reference.

#define TOPK 16
#define NSAMP 8
#define MDIM 256
#define BN_TOTAL 8192
#define KINF 0xFFFFFFFFu

__device__ __forceinline__ unsigned mono(float v) {
  unsigned b = __float_as_uint(v);
  // monotone map: ascending u <=> ascending v (total order)
  return (b & 0x80000000u) ? ~b : (b | 0x80000000u);
}

template <int CTRL>
__device__ __forceinline__ unsigned dpp_min_step(unsigned v) {
  unsigned o = (unsigned)__builtin_amdgcn_update_dpp((int)v, (int)v, CTRL,
                                                     0xF, 0xF, false);
  return o < v ? o : v;
}

__global__ __launch_bounds__(256) void soft_topk_kernel(
    const float* __restrict__ x, const float* __restrict__ noise,
    float* __restrict__ out) {
  const int bn = blockIdx.x;
  const int tid = threadIdx.x;
  const int wave = tid >> 6;
  const int lane = tid & 63;

  __shared__ __align__(16) float counts[TOPK * MDIM];  // 16 KiB
  {
    float4* cz = reinterpret_cast<float4*>(counts);
#pragma unroll
    for (int i = 0; i < 4; ++i)
      cz[tid + 256 * i] = make_float4(0.f, 0.f, 0.f, 0.f);
  }
  __syncthreads();

  const int mbase = lane * 4;
  const float4 x4 =
      *reinterpret_cast<const float4*>(x + (size_t)bn * MDIM + mbase);
  const int sA = wave * 2;
  const float4 nA = *reinterpret_cast<const float4*>(
      noise + ((size_t)bn * NSAMP + sA) * MDIM + mbase);
  const float4 nB = *reinterpret_cast<const float4*>(
      noise + ((size_t)bn * NSAMP + sA + 1) * MDIM + mbase);

  // no-contract: bit-match reference's (x + noise*sigma) in fp32
  unsigned kA0 = mono(__fadd_rn(x4.x, __fmul_rn(nA.x, 1e-4f)));
  unsigned kA1 = mono(__fadd_rn(x4.y, __fmul_rn(nA.y, 1e-4f)));
  unsigned kA2 = mono(__fadd_rn(x4.z, __fmul_rn(nA.z, 1e-4f)));
  unsigned kA3 = mono(__fadd_rn(x4.w, __fmul_rn(nA.w, 1e-4f)));
  unsigned kB0 = mono(__fadd_rn(x4.x, __fmul_rn(nB.x, 1e-4f)));
  unsigned kB1 = mono(__fadd_rn(x4.y, __fmul_rn(nB.y, 1e-4f)));
  unsigned kB2 = mono(__fadd_rn(x4.z, __fmul_rn(nB.z, 1e-4f)));
  unsigned kB3 = mono(__fadd_rn(x4.w, __fmul_rn(nB.w, 1e-4f)));

  const unsigned sid0 = (unsigned)mbase;
  const unsigned sid1 = (unsigned)mbase + 1u;
  const unsigned sid2 = (unsigned)mbase + 2u;
  const unsigned sid3 = (unsigned)mbase + 3u;

  unsigned capA = 0, capB = 0;  // m captured by lane==rank
#pragma unroll
  for (int it = 0; it < TOPK; ++it) {
    // per-lane min + slot, <= prefers lower slot (stable)
    const bool a01 = kA0 <= kA1;
    const unsigned aa = a01 ? kA0 : kA1;
    const unsigned asa = a01 ? 0u : 1u;
    const bool a23 = kA2 <= kA3;
    const unsigned ab = a23 ? kA2 : kA3;
    const unsigned asb = a23 ? 2u : 3u;
    const bool aab = aa <= ab;
    const unsigned lminA = aab ? aa : ab;
    const unsigned lslotA = aab ? asa : asb;

    const bool b01 = kB0 <= kB1;
    const unsigned ba = b01 ? kB0 : kB1;
    const unsigned bsa = b01 ? 0u : 1u;
    const bool b23 = kB2 <= kB3;
    const unsigned bb = b23 ? kB2 : kB3;
    const unsigned bsb = b23 ? 2u : 3u;
    const bool bab = ba <= bb;
    const unsigned lminB = bab ? ba : bb;
    const unsigned lslotB = bab ? bsa : bsb;

    // two independent 64-lane DPP min cascades, interleaved for ILP
    unsigned gA = lminA, gB = lminB;
    gA = dpp_min_step<0xB1>(gA);   gB = dpp_min_step<0xB1>(gB);   // xor1
    gA = dpp_min_step<0x4E>(gA);   gB = dpp_min_step<0x4E>(gB);   // xor2
    gA = dpp_min_step<0x141>(gA);  gB = dpp_min_step<0x141>(gB);  // half_mirror
    gA = dpp_min_step<0x140>(gA);  gB = dpp_min_step<0x140>(gB);  // mirror
    gA = dpp_min_step<0x142>(gA);  gB = dpp_min_step<0x142>(gB);  // bcast15
    gA = dpp_min_step<0x143>(gA);  gB = dpp_min_step<0x143>(gB);  // bcast31
    const unsigned gminA = (unsigned)__builtin_amdgcn_readlane((int)gA, 63);
    const unsigned gminB = (unsigned)__builtin_amdgcn_readlane((int)gB, 63);

    // winner = lowest lane matching the global min (m = lane*4+slot, so
    // lowest lane wins regardless of slot), then its lowest slot
    const unsigned long long mA = __ballot(lminA == gminA);
    const unsigned long long mB = __ballot(lminB == gminB);
    const int wlA = __ffsll(mA) - 1;
    const int wlB = __ffsll(mB) - 1;
    const unsigned wsA = (unsigned)__builtin_amdgcn_readlane((int)lslotA, wlA);
    const unsigned wsB = (unsigned)__builtin_amdgcn_readlane((int)lslotB, wlB);
    const unsigned mwA = ((unsigned)wlA << 2) | wsA;
    const unsigned mwB = ((unsigned)wlB << 2) | wsB;

    capA = (lane == it) ? mwA : capA;
    capB = (lane == it) ? mwB : capB;

    if (it < TOPK - 1) {  // branchless invalidation of the extracted slot
      kA0 = (sid0 == mwA) ? KINF : kA0;
      kA1 = (sid1 == mwA) ? KINF : kA1;
      kA2 = (sid2 == mwA) ? KINF : kA2;
      kA3 = (sid3 == mwA) ? KINF : kA3;
      kB0 = (sid0 == mwB) ? KINF : kB0;
      kB1 = (sid1 == mwB) ? KINF : kB1;
      kB2 = (sid2 == mwB) ? KINF : kB2;
      kB3 = (sid3 == mwB) ? KINF : kB3;
    }
  }

  if (lane < TOPK) {
    atomicAdd(&counts[lane * MDIM + capA], 0.125f);
    atomicAdd(&counts[lane * MDIM + capB], 0.125f);
  }
  __syncthreads();

  // write 16x256 floats, coalesced float4
  float4* outv = reinterpret_cast<float4*>(out + (size_t)bn * (TOPK * MDIM));
  const float4* cv = reinterpret_cast<const float4*>(counts);
#pragma unroll
  for (int i = 0; i < 4; ++i) outv[tid + 256 * i] = cv[tid + 256 * i];
}

extern "C" void kernel_launch(void* const* d_in, const int* in_sizes, int n_in,
                              void* d_out, int out_size, void* d_ws,
                              size_t ws_size, hipStream_t stream) {
  const float* x = (const float*)d_in[0];
  const float* noise = (const float*)d_in[1];
  float* out = (float*)d_out;
  soft_topk_kernel<<<BN_TOTAL, 256, 0, stream>>>(x, noise, out);
}